// Round 1
// baseline (868.939 us; speedup 1.0000x reference)
//
#include <hip/hip_runtime.h>
#include <math.h>

#define NN 8192
#define EE 81920
#define E2C 1310720
#define HSZ (1 << 18)
#define HMASK (HSZ - 1)

__device__ __forceinline__ float wsum(float v) {
#pragma unroll
  for (int m = 32; m > 0; m >>= 1) v += __shfl_xor(v, m, 64);
  return v;
}
__device__ __forceinline__ float lrelu(float x) { return x > 0.f ? x : 0.2f * x; }

// P = embed @ gat_W[0:128], Q = embed @ gat_W[128:256]   (one wave per node)
__global__ __launch_bounds__(256) void k_pq(const float* __restrict__ embed,
                                            const float* __restrict__ gw,
                                            float* __restrict__ P, float* __restrict__ Q) {
  __shared__ float Wl[256 * 64];  // 64 KB, plain layout: 2-way bank alias (free)
  for (int i = threadIdx.x; i < 256 * 64; i += 256) Wl[i] = gw[i];
  __syncthreads();
  int lane = threadIdx.x & 63;
  int n = blockIdx.x * 4 + (threadIdx.x >> 6);
  float h0 = embed[n * 128 + lane];
  float h1 = embed[n * 128 + 64 + lane];
  float p = 0.f, q = 0.f;
#pragma unroll
  for (int k = 0; k < 64; k++) {
    float a = __shfl(h0, k, 64);
    float b = __shfl(h1, k, 64);
    p += a * Wl[k * 64 + lane];
    p += b * Wl[(64 + k) * 64 + lane];
    q += a * Wl[(128 + k) * 64 + lane];
    q += b * Wl[(192 + k) * 64 + lane];
  }
  P[n * 64 + lane] = p;
  Q[n * 64 + lane] = q;
}

// per-edge attention scalars: a_s[e] = hp[e]@att_src, a_d[e] = hp[e]@att_dst
__global__ __launch_bounds__(256) void k_asd(const float* __restrict__ P, const float* __restrict__ Q,
                                             const int* __restrict__ row, const int* __restrict__ col,
                                             const float* __restrict__ att_s, const float* __restrict__ att_d,
                                             float* __restrict__ a_s, float* __restrict__ a_d) {
  int lane = threadIdx.x & 63;
  int e = blockIdx.x * 4 + (threadIdx.x >> 6);
  int r = row[e], c = col[e];
  float v = P[r * 64 + lane] + Q[c * 64 + lane];
  float s1 = wsum(v * att_s[lane]);
  float s2 = wsum(v * att_d[lane]);
  if (lane == 0) { a_s[e] = s1; a_d[e] = s2; }
}

__global__ void k_count(const int* __restrict__ idx, int n, int* __restrict__ cnt) {
  int i = blockIdx.x * blockDim.x + threadIdx.x;
  if (i < n) atomicAdd(&cnt[idx[i]], 1);
}

// single-block exclusive scan; also copies offsets into a cursor array
__global__ __launch_bounds__(1024) void k_scan(const int* __restrict__ cnt, int n,
                                               int* __restrict__ offs, int* __restrict__ cur) {
  __shared__ int sd[1024];
  int t = threadIdx.x;
  int C = (n + 1023) >> 10;
  int beg = t * C, end = min(beg + C, n);
  int s = 0;
  for (int i = beg; i < end; i++) s += cnt[i];
  sd[t] = s;
  __syncthreads();
  for (int off = 1; off < 1024; off <<= 1) {
    int v = (t >= off) ? sd[t - off] : 0;
    __syncthreads();
    sd[t] += v;
    __syncthreads();
  }
  int run = (t == 0) ? 0 : sd[t - 1];
  for (int i = beg; i < end; i++) {
    offs[i] = run;
    cur[i] = run;
    run += cnt[i];
  }
  if (t == 0) offs[n] = sd[1023];
}

__global__ void k_scatter_dst(const int* __restrict__ src2, const int* __restrict__ dst2,
                              int* __restrict__ cur, int* __restrict__ csrSrc) {
  int i = blockIdx.x * blockDim.x + threadIdx.x;
  if (i < E2C) {
    int d = dst2[i];
    int pos = atomicAdd(&cur[d], 1);
    csrSrc[pos] = src2[i];
  }
}

// one wave per destination edge-node: softmax attention + weighted aggregation + lin + gate
__global__ __launch_bounds__(256) void k_gat(const float* __restrict__ P, const float* __restrict__ Q,
                                             const int* __restrict__ row, const int* __restrict__ col,
                                             const float* __restrict__ a_s, const float* __restrict__ a_d,
                                             const int* __restrict__ dstOffs, const int* __restrict__ csrSrc,
                                             const float* __restrict__ gat_bias, const float* __restrict__ lin_W,
                                             const float* __restrict__ lin_b, const float* __restrict__ noise,
                                             const float* __restrict__ tmp, float* __restrict__ gate) {
  int lane = threadIdx.x & 63;
  int e = blockIdx.x * 4 + (threadIdx.x >> 6);
  int off = dstOffs[e], end = dstOffs[e + 1];
  float ade = a_d[e];
  float eself = expf(lrelu(a_s[e] + ade));  // self-loop term (softmax shift-invariant: skip segment_max)
  float part = 0.f;
  for (int i = off + lane; i < end; i += 64) {
    int s = csrSrc[i];
    part += expf(lrelu(a_s[s] + ade));
  }
  float denom = wsum(part) + eself;
  float inv = 1.0f / denom;
  int r = row[e], c = col[e];
  float acc = eself * inv * (P[r * 64 + lane] + Q[c * 64 + lane]);
  for (int i = off; i < end; i++) {
    int s = csrSrc[i];
    float w = expf(lrelu(a_s[s] + ade)) * inv;
    int rs = row[s], cs = col[s];
    acc += w * (P[rs * 64 + lane] + Q[cs * 64 + lane]);
  }
  float go = acc + gat_bias[lane];
  float la = wsum(go * lin_W[lane]);
  if (lane == 0) {
    float lo = la + lin_b[0];
    float ns = noise[e];
    float g = (logf(ns) - log1pf(-ns) + lo) / tmp[0];
    gate[e] = 1.0f / (1.0f + expf(-g));
  }
}

// hash-table accumulate of (count, gate-sum) per unique (r,c) pair — replaces 2x 256MB dense N x N
__global__ void k_hash_build(const int* __restrict__ row, const int* __restrict__ col,
                             const float* __restrict__ gate, int* __restrict__ keys,
                             float* __restrict__ cnt, float* __restrict__ gsum) {
  int e = blockIdx.x * blockDim.x + threadIdx.x;
  if (e >= EE) return;
  int key = row[e] * NN + col[e];
  unsigned i = ((unsigned)key * 2654435761u) >> 14 & HMASK;
  while (true) {
    int old = atomicCAS(&keys[i], -1, key);
    if (old == -1 || old == key) break;
    i = (i + 1) & HMASK;
  }
  atomicAdd(&cnt[i], 1.0f);
  atomicAdd(&gsum[i], gate[e]);
}

__device__ __forceinline__ int hfind(const int* __restrict__ keys, int key) {
  unsigned i = ((unsigned)key * 2654435761u) >> 14 & HMASK;
  while (true) {
    int k = keys[i];
    if (k == key) return (int)i;
    if (k == -1) return -1;
    i = (i + 1) & HMASK;
  }
}

// edge_mask -> w = sigmoid(mask); also deg accumulation and col-CSR counting
__global__ void k_edge_w(const int* __restrict__ row, const int* __restrict__ col,
                         const int* __restrict__ keys, const float* __restrict__ cnt,
                         const float* __restrict__ gsum, float* __restrict__ wE,
                         float* __restrict__ degsum, int* __restrict__ colCnt) {
  int e = blockIdx.x * blockDim.x + threadIdx.x;
  if (e >= EE) return;
  int r = row[e], c = col[e];
  int s1 = hfind(keys, r * NN + c);  // always present (edge e itself)
  float cv = cnt[s1], g1 = gsum[s1];
  int s2 = hfind(keys, c * NN + r);
  float g2 = (s2 >= 0) ? gsum[s2] : 0.f;
  float em = cv * 0.5f * (g1 + g2);  // adj * (S + S^T)/2 at (r,c)
  float w = 1.f / (1.f + expf(-em));
  wE[e] = w;
  atomicAdd(&degsum[c], w);
  atomicAdd(&colCnt[c], 1);
}

__global__ void k_scatter_col(const int* __restrict__ col, int* __restrict__ cur, int* __restrict__ eid) {
  int e = blockIdx.x * blockDim.x + threadIdx.x;
  if (e >= EE) return;
  int pos = atomicAdd(&cur[col[e]], 1);
  eid[pos] = e;
}

// t[n] = (xh[n] + sum_{e: col=n} w_e * xh[row_e]) / (1+degsum[n])   (one wave per node, lane owns 2 dims)
__global__ __launch_bounds__(256) void k_gather(const float* __restrict__ xh, const float* __restrict__ wE,
                                                const int* __restrict__ row, const int* __restrict__ colOffs,
                                                const int* __restrict__ colEid, const float* __restrict__ degsum,
                                                float* __restrict__ T) {
  int lane = threadIdx.x & 63;
  int n = blockIdx.x * 4 + (threadIdx.x >> 6);
  float a0 = xh[n * 128 + lane], a1 = xh[n * 128 + 64 + lane];
  int off = colOffs[n], end = colOffs[n + 1];
  for (int i = off; i < end; i++) {
    int e = colEid[i];
    float wv = wE[e];
    int r = row[e];
    a0 += wv * xh[r * 128 + lane];
    a1 += wv * xh[r * 128 + 64 + lane];
  }
  float inv = 1.f / (1.f + degsum[n]);
  T[n * 128 + lane] = a0 * inv;
  T[n * 128 + 64 + lane] = a1 * inv;
}

// out = relu(T @ W), W 128x128 in LDS (64 KB), one wave per node
__global__ __launch_bounds__(256) void k_gemm128(const float* __restrict__ T, const float* __restrict__ W,
                                                 float* __restrict__ out) {
  __shared__ float Wl[128 * 128];
  for (int i = threadIdx.x; i < 128 * 128; i += 256) Wl[i] = W[i];
  __syncthreads();
  int lane = threadIdx.x & 63;
  int n = blockIdx.x * 4 + (threadIdx.x >> 6);
  float t0 = T[n * 128 + lane], t1 = T[n * 128 + 64 + lane];
  float a0 = 0.f, a1 = 0.f;
#pragma unroll
  for (int k = 0; k < 64; k++) {
    float ta = __shfl(t0, k, 64);
    float tb = __shfl(t1, k, 64);
    a0 += ta * Wl[k * 128 + lane];
    a1 += ta * Wl[k * 128 + 64 + lane];
    a0 += tb * Wl[(64 + k) * 128 + lane];
    a1 += tb * Wl[(64 + k) * 128 + 64 + lane];
  }
  out[n * 128 + lane] = fmaxf(a0, 0.f);
  out[n * 128 + 64 + lane] = fmaxf(a1, 0.f);
}

__global__ __launch_bounds__(256) void k_pool(const float* __restrict__ H, float* __restrict__ gvec) {
  int t = threadIdx.x;
  int d = t & 127;
  int h = t >> 7;
  int base = blockIdx.x * 64;
  float s = 0.f;
  for (int n = base + h; n < base + 64; n += 2) s += H[n * 128 + d];
  __shared__ float sd[256];
  sd[t] = s;
  __syncthreads();
  if (h == 0) atomicAdd(&gvec[d], sd[t] + sd[t + 128]);
}

__global__ __launch_bounds__(128) void k_final(const float* __restrict__ gvec, const float* __restrict__ Wc,
                                               float* __restrict__ out) {
  int j = threadIdx.x;
  float gj = gvec[j] * (1.0f / 8192.0f);
  __shared__ float s0[128], s1[128];
  s0[j] = gj * Wc[j * 2 + 0];
  s1[j] = gj * Wc[j * 2 + 1];
  __syncthreads();
  for (int o = 64; o > 0; o >>= 1) {
    if (j < o) {
      s0[j] += s0[j + o];
      s1[j] += s1[j + o];
    }
    __syncthreads();
  }
  if (j == 0) {
    float l0 = s0[0], l1 = s1[0];
    float m = fmaxf(l0, l1);
    float e0 = expf(l0 - m), e1 = expf(l1 - m);
    float inv = 1.f / (e0 + e1);
    out[0] = e0 * inv;
    out[1] = e1 * inv;
  }
}

extern "C" void kernel_launch(void* const* d_in, const int* in_sizes, int n_in,
                              void* d_out, int out_size, void* d_ws, size_t ws_size,
                              hipStream_t stream) {
  const float* x     = (const float*)d_in[0];
  const float* embed = (const float*)d_in[1];
  const float* noise = (const float*)d_in[2];
  const float* tmp   = (const float*)d_in[3];
  const float* gat_W = (const float*)d_in[4];
  const float* att_s = (const float*)d_in[5];
  const float* att_d = (const float*)d_in[6];
  const float* gat_b = (const float*)d_in[7];
  const float* lin_W = (const float*)d_in[8];
  const float* lin_b = (const float*)d_in[9];
  const float* W1    = (const float*)d_in[10];
  const float* W2    = (const float*)d_in[11];
  const float* W3    = (const float*)d_in[12];
  const float* Wc    = (const float*)d_in[13];
  const int* ei      = (const int*)d_in[14];
  const int* nei     = (const int*)d_in[15];
  const int* row = ei;
  const int* col = ei + EE;
  const int* src2 = nei;
  const int* dst2 = nei + E2C;
  float* out = (float*)d_out;

  // workspace layout (4-byte units) — total ~24 MB
  char* w8 = (char*)d_ws;
  size_t off = 0;
  auto alloc = [&](size_t units) -> void* {
    void* p = w8 + off * 4;
    off += units;
    return p;
  };
  float* a_s      = (float*)alloc(EE);
  float* a_d      = (float*)alloc(EE);
  float* gate     = (float*)alloc(EE);
  float* wE       = (float*)alloc(EE);
  float* P        = (float*)alloc(NN * 64);
  float* Q        = (float*)alloc(NN * 64);
  // contiguous zero region:
  float* degsum   = (float*)alloc(NN);
  float* gvec     = (float*)alloc(128);
  int*   cntDst   = (int*)alloc(EE);
  int*   colCnt   = (int*)alloc(NN);
  // no-init region:
  int*   dstOffs  = (int*)alloc(EE + 1);
  int*   dstCur   = (int*)alloc(EE);
  int*   csrSrc   = (int*)alloc(E2C);
  int*   colOffs  = (int*)alloc(NN + 1);
  int*   colCur   = (int*)alloc(NN);
  int*   colEid   = (int*)alloc(EE);
  // hash
  int*   hKeys    = (int*)alloc(HSZ);
  float* hCnt     = (float*)alloc(HSZ);  // contiguous with hGsum, zeroed together
  float* hGsum    = (float*)alloc(HSZ);
  float* T        = (float*)alloc(NN * 128);
  float* Hbuf     = (float*)alloc(NN * 128);

  hipMemsetAsync(degsum, 0, (size_t)(NN + 128 + EE + NN) * 4, stream);
  hipMemsetAsync(hKeys, 0xFF, (size_t)HSZ * 4, stream);
  hipMemsetAsync(hCnt, 0, (size_t)2 * HSZ * 4, stream);

  k_pq<<<NN / 4, 256, 0, stream>>>(embed, gat_W, P, Q);
  k_asd<<<EE / 4, 256, 0, stream>>>(P, Q, row, col, att_s, att_d, a_s, a_d);
  k_count<<<E2C / 256, 256, 0, stream>>>(dst2, E2C, cntDst);
  k_scan<<<1, 1024, 0, stream>>>(cntDst, EE, dstOffs, dstCur);
  k_scatter_dst<<<E2C / 256, 256, 0, stream>>>(src2, dst2, dstCur, csrSrc);
  k_gat<<<EE / 4, 256, 0, stream>>>(P, Q, row, col, a_s, a_d, dstOffs, csrSrc,
                                    gat_b, lin_W, lin_b, noise, tmp, gate);
  k_hash_build<<<EE / 256, 256, 0, stream>>>(row, col, gate, hKeys, hCnt, hGsum);
  k_edge_w<<<EE / 256, 256, 0, stream>>>(row, col, hKeys, hCnt, hGsum, wE, degsum, colCnt);
  k_scan<<<1, 1024, 0, stream>>>(colCnt, NN, colOffs, colCur);
  k_scatter_col<<<EE / 256, 256, 0, stream>>>(col, colCur, colEid);

  // 3-layer edge-weighted GCN
  k_gather<<<NN / 4, 256, 0, stream>>>(x, wE, row, colOffs, colEid, degsum, T);
  k_gemm128<<<NN / 4, 256, 0, stream>>>(T, W1, Hbuf);
  k_gather<<<NN / 4, 256, 0, stream>>>(Hbuf, wE, row, colOffs, colEid, degsum, T);
  k_gemm128<<<NN / 4, 256, 0, stream>>>(T, W2, Hbuf);
  k_gather<<<NN / 4, 256, 0, stream>>>(Hbuf, wE, row, colOffs, colEid, degsum, T);
  k_gemm128<<<NN / 4, 256, 0, stream>>>(T, W3, Hbuf);

  k_pool<<<NN / 64, 256, 0, stream>>>(Hbuf, gvec);
  k_final<<<1, 128, 0, stream>>>(gvec, Wc, out);
}

// Round 2
// 478.515 us; speedup vs baseline: 1.8159x; 1.8159x over previous
//
#include <hip/hip_runtime.h>
#include <math.h>

#define NN 8192
#define EE 81920
#define E2C 1310720
#define HSZ (1 << 18)
#define HMASK (HSZ - 1)

__device__ __forceinline__ float wsum(float v) {
#pragma unroll
  for (int m = 32; m > 0; m >>= 1) v += __shfl_xor(v, m, 64);
  return v;
}
__device__ __forceinline__ float lrelu(float x) { return x > 0.f ? x : 0.2f * x; }

// P = embed @ gat_W[0:128], Q = embed @ gat_W[128:256]   (one wave per node)
__global__ __launch_bounds__(256) void k_pq(const float* __restrict__ embed,
                                            const float* __restrict__ gw,
                                            float* __restrict__ P, float* __restrict__ Q) {
  __shared__ float Wl[256 * 64];  // 64 KB, plain layout: 2-way bank alias (free)
  for (int i = threadIdx.x; i < 256 * 64; i += 256) Wl[i] = gw[i];
  __syncthreads();
  int lane = threadIdx.x & 63;
  int n = blockIdx.x * 4 + (threadIdx.x >> 6);
  float h0 = embed[n * 128 + lane];
  float h1 = embed[n * 128 + 64 + lane];
  float p = 0.f, q = 0.f;
#pragma unroll
  for (int k = 0; k < 64; k++) {
    float a = __shfl(h0, k, 64);
    float b = __shfl(h1, k, 64);
    p += a * Wl[k * 64 + lane];
    p += b * Wl[(64 + k) * 64 + lane];
    q += a * Wl[(128 + k) * 64 + lane];
    q += b * Wl[(192 + k) * 64 + lane];
  }
  P[n * 64 + lane] = p;
  Q[n * 64 + lane] = q;
}

// per-edge scalars: a_s = hp@att_src, a_d = hp@att_dst, z = hp@lin_W
__global__ __launch_bounds__(256) void k_asd(const float* __restrict__ P, const float* __restrict__ Q,
                                             const int* __restrict__ row, const int* __restrict__ col,
                                             const float* __restrict__ att_s, const float* __restrict__ att_d,
                                             const float* __restrict__ lin_W,
                                             float* __restrict__ a_s, float* __restrict__ a_d,
                                             float* __restrict__ z) {
  int lane = threadIdx.x & 63;
  int e = blockIdx.x * 4 + (threadIdx.x >> 6);
  int r = row[e], c = col[e];
  float v = P[r * 64 + lane] + Q[c * 64 + lane];
  float s1 = wsum(v * att_s[lane]);
  float s2 = wsum(v * att_d[lane]);
  float s3 = wsum(v * lin_W[lane]);
  if (lane == 0) { a_s[e] = s1; a_d[e] = s2; z[e] = s3; }
}

// edge2-parallel scalar GAT accumulation: denom/numer per destination edge-node.
// Linearity trick: log_alpha[d] only needs hp[s]@lin_W (= z[s]), not the 64-dim hp.
__global__ void k_acc(const int* __restrict__ src2, const int* __restrict__ dst2,
                      const float* __restrict__ a_s, const float* __restrict__ a_d,
                      const float* __restrict__ z,
                      float* __restrict__ denom, float* __restrict__ numer) {
  int i = blockIdx.x * blockDim.x + threadIdx.x;
  if (i >= E2C) return;
  int s = src2[i], d = dst2[i];
  float ea = expf(lrelu(a_s[s] + a_d[d]));
  atomicAdd(&denom[d], ea);
  atomicAdd(&numer[d], ea * z[s]);
}

// per-edge: add self-loop term, divide, add bias scalar, concrete gate
__global__ __launch_bounds__(256) void k_gate(const float* __restrict__ a_s, const float* __restrict__ a_d,
                                              const float* __restrict__ z,
                                              const float* __restrict__ denom, const float* __restrict__ numer,
                                              const float* __restrict__ gat_bias, const float* __restrict__ lin_W,
                                              const float* __restrict__ lin_b, const float* __restrict__ noise,
                                              const float* __restrict__ tmp, float* __restrict__ gate) {
  int lane = threadIdx.x & 63;
  float gb = wsum(gat_bias[lane] * lin_W[lane]);  // all lanes receive the sum
  int e = blockIdx.x * 256 + threadIdx.x;
  float as = a_s[e], ad = a_d[e];
  float eself = expf(lrelu(as + ad));  // softmax shift-invariance: skip segment_max
  float la = (numer[e] + eself * z[e]) / (denom[e] + eself) + gb + lin_b[0];
  float ns = noise[e];
  float g = (logf(ns) - log1pf(-ns) + la) / tmp[0];
  gate[e] = 1.0f / (1.0f + expf(-g));
}

// hash-table accumulate of (count, gate-sum) per unique (r,c) pair — replaces 2x 256MB dense N x N
__global__ void k_hash_build(const int* __restrict__ row, const int* __restrict__ col,
                             const float* __restrict__ gate, int* __restrict__ keys,
                             float* __restrict__ cnt, float* __restrict__ gsum) {
  int e = blockIdx.x * blockDim.x + threadIdx.x;
  if (e >= EE) return;
  int key = row[e] * NN + col[e];
  unsigned i = ((unsigned)key * 2654435761u) >> 14 & HMASK;
  while (true) {
    int old = atomicCAS(&keys[i], -1, key);
    if (old == -1 || old == key) break;
    i = (i + 1) & HMASK;
  }
  atomicAdd(&cnt[i], 1.0f);
  atomicAdd(&gsum[i], gate[e]);
}

__device__ __forceinline__ int hfind(const int* __restrict__ keys, int key) {
  unsigned i = ((unsigned)key * 2654435761u) >> 14 & HMASK;
  while (true) {
    int k = keys[i];
    if (k == key) return (int)i;
    if (k == -1) return -1;
    i = (i + 1) & HMASK;
  }
}

// edge_mask -> w = sigmoid(mask); also deg accumulation and col-CSR counting
__global__ void k_edge_w(const int* __restrict__ row, const int* __restrict__ col,
                         const int* __restrict__ keys, const float* __restrict__ cnt,
                         const float* __restrict__ gsum, float* __restrict__ wE,
                         float* __restrict__ degsum, int* __restrict__ colCnt) {
  int e = blockIdx.x * blockDim.x + threadIdx.x;
  if (e >= EE) return;
  int r = row[e], c = col[e];
  int s1 = hfind(keys, r * NN + c);  // always present (edge e itself)
  float cv = cnt[s1], g1 = gsum[s1];
  int s2 = hfind(keys, c * NN + r);
  float g2 = (s2 >= 0) ? gsum[s2] : 0.f;
  float em = cv * 0.5f * (g1 + g2);  // adj * (S + S^T)/2 at (r,c)
  float w = 1.f / (1.f + expf(-em));
  wE[e] = w;
  atomicAdd(&degsum[c], w);
  atomicAdd(&colCnt[c], 1);
}

// single-block exclusive scan; also copies offsets into a cursor array
__global__ __launch_bounds__(1024) void k_scan(const int* __restrict__ cnt, int n,
                                               int* __restrict__ offs, int* __restrict__ cur) {
  __shared__ int sd[1024];
  int t = threadIdx.x;
  int C = (n + 1023) >> 10;
  int beg = t * C, end = min(beg + C, n);
  int s = 0;
  for (int i = beg; i < end; i++) s += cnt[i];
  sd[t] = s;
  __syncthreads();
  for (int off = 1; off < 1024; off <<= 1) {
    int v = (t >= off) ? sd[t - off] : 0;
    __syncthreads();
    sd[t] += v;
    __syncthreads();
  }
  int run = (t == 0) ? 0 : sd[t - 1];
  for (int i = beg; i < end; i++) {
    offs[i] = run;
    cur[i] = run;
    run += cnt[i];
  }
  if (t == 0) offs[n] = sd[1023];
}

__global__ void k_scatter_col(const int* __restrict__ col, int* __restrict__ cur, int* __restrict__ eid) {
  int e = blockIdx.x * blockDim.x + threadIdx.x;
  if (e >= EE) return;
  int pos = atomicAdd(&cur[col[e]], 1);
  eid[pos] = e;
}

// t[n] = (xh[n] + sum_{e: col=n} w_e * xh[row_e]) / (1+degsum[n])   (one wave per node)
__global__ __launch_bounds__(256) void k_gather(const float* __restrict__ xh, const float* __restrict__ wE,
                                                const int* __restrict__ row, const int* __restrict__ colOffs,
                                                const int* __restrict__ colEid, const float* __restrict__ degsum,
                                                float* __restrict__ T) {
  int lane = threadIdx.x & 63;
  int n = blockIdx.x * 4 + (threadIdx.x >> 6);
  float a0 = xh[n * 128 + lane], a1 = xh[n * 128 + 64 + lane];
  int off = colOffs[n], end = colOffs[n + 1];
  for (int i = off; i < end; i++) {
    int e = colEid[i];
    float wv = wE[e];
    int r = row[e];
    a0 += wv * xh[r * 128 + lane];
    a1 += wv * xh[r * 128 + 64 + lane];
  }
  float inv = 1.f / (1.f + degsum[n]);
  T[n * 128 + lane] = a0 * inv;
  T[n * 128 + 64 + lane] = a1 * inv;
}

// out = relu(T @ W), W 128x128 in LDS (64 KB), one wave per node
__global__ __launch_bounds__(256) void k_gemm128(const float* __restrict__ T, const float* __restrict__ W,
                                                 float* __restrict__ out) {
  __shared__ float Wl[128 * 128];
  for (int i = threadIdx.x; i < 128 * 128; i += 256) Wl[i] = W[i];
  __syncthreads();
  int lane = threadIdx.x & 63;
  int n = blockIdx.x * 4 + (threadIdx.x >> 6);
  float t0 = T[n * 128 + lane], t1 = T[n * 128 + 64 + lane];
  float a0 = 0.f, a1 = 0.f;
#pragma unroll
  for (int k = 0; k < 64; k++) {
    float ta = __shfl(t0, k, 64);
    float tb = __shfl(t1, k, 64);
    a0 += ta * Wl[k * 128 + lane];
    a1 += ta * Wl[k * 128 + 64 + lane];
    a0 += tb * Wl[(64 + k) * 128 + lane];
    a1 += tb * Wl[(64 + k) * 128 + 64 + lane];
  }
  out[n * 128 + lane] = fmaxf(a0, 0.f);
  out[n * 128 + 64 + lane] = fmaxf(a1, 0.f);
}

__global__ __launch_bounds__(256) void k_pool(const float* __restrict__ H, float* __restrict__ gvec) {
  int t = threadIdx.x;
  int d = t & 127;
  int h = t >> 7;
  int base = blockIdx.x * 64;
  float s = 0.f;
  for (int n = base + h; n < base + 64; n += 2) s += H[n * 128 + d];
  __shared__ float sd[256];
  sd[t] = s;
  __syncthreads();
  if (h == 0) atomicAdd(&gvec[d], sd[t] + sd[t + 128]);
}

__global__ __launch_bounds__(128) void k_final(const float* __restrict__ gvec, const float* __restrict__ Wc,
                                               float* __restrict__ out) {
  int j = threadIdx.x;
  float gj = gvec[j] * (1.0f / 8192.0f);
  __shared__ float s0[128], s1[128];
  s0[j] = gj * Wc[j * 2 + 0];
  s1[j] = gj * Wc[j * 2 + 1];
  __syncthreads();
  for (int o = 64; o > 0; o >>= 1) {
    if (j < o) {
      s0[j] += s0[j + o];
      s1[j] += s1[j + o];
    }
    __syncthreads();
  }
  if (j == 0) {
    float l0 = s0[0], l1 = s1[0];
    float m = fmaxf(l0, l1);
    float e0 = expf(l0 - m), e1 = expf(l1 - m);
    float inv = 1.f / (e0 + e1);
    out[0] = e0 * inv;
    out[1] = e1 * inv;
  }
}

extern "C" void kernel_launch(void* const* d_in, const int* in_sizes, int n_in,
                              void* d_out, int out_size, void* d_ws, size_t ws_size,
                              hipStream_t stream) {
  const float* x     = (const float*)d_in[0];
  const float* embed = (const float*)d_in[1];
  const float* noise = (const float*)d_in[2];
  const float* tmp   = (const float*)d_in[3];
  const float* gat_W = (const float*)d_in[4];
  const float* att_s = (const float*)d_in[5];
  const float* att_d = (const float*)d_in[6];
  const float* gat_b = (const float*)d_in[7];
  const float* lin_W = (const float*)d_in[8];
  const float* lin_b = (const float*)d_in[9];
  const float* W1    = (const float*)d_in[10];
  const float* W2    = (const float*)d_in[11];
  const float* W3    = (const float*)d_in[12];
  const float* Wc    = (const float*)d_in[13];
  const int* ei      = (const int*)d_in[14];
  const int* nei     = (const int*)d_in[15];
  const int* row = ei;
  const int* col = ei + EE;
  const int* src2 = nei;
  const int* dst2 = nei + E2C;
  float* out = (float*)d_out;

  // workspace layout (4-byte units) — total ~18.5 MB
  char* w8 = (char*)d_ws;
  size_t off = 0;
  auto alloc = [&](size_t units) -> void* {
    void* p = w8 + off * 4;
    off += units;
    return p;
  };
  float* a_s      = (float*)alloc(EE);
  float* a_d      = (float*)alloc(EE);
  float* z        = (float*)alloc(EE);
  float* gate     = (float*)alloc(EE);
  float* wE       = (float*)alloc(EE);
  float* P        = (float*)alloc(NN * 64);
  float* Q        = (float*)alloc(NN * 64);
  // contiguous zero region:
  float* degsum   = (float*)alloc(NN);
  float* gvec     = (float*)alloc(128);
  int*   colCnt   = (int*)alloc(NN);
  float* denom    = (float*)alloc(EE);
  float* numer    = (float*)alloc(EE);
  // no-init region:
  int*   colOffs  = (int*)alloc(NN + 1);
  int*   colCur   = (int*)alloc(NN);
  int*   colEid   = (int*)alloc(EE);
  // hash
  int*   hKeys    = (int*)alloc(HSZ);
  float* hCnt     = (float*)alloc(HSZ);  // contiguous with hGsum, zeroed together
  float* hGsum    = (float*)alloc(HSZ);
  float* T        = (float*)alloc(NN * 128);
  float* Hbuf     = (float*)alloc(NN * 128);

  hipMemsetAsync(degsum, 0, (size_t)(NN + 128 + NN + 2 * EE) * 4, stream);
  hipMemsetAsync(hKeys, 0xFF, (size_t)HSZ * 4, stream);
  hipMemsetAsync(hCnt, 0, (size_t)2 * HSZ * 4, stream);

  k_pq<<<NN / 4, 256, 0, stream>>>(embed, gat_W, P, Q);
  k_asd<<<EE / 4, 256, 0, stream>>>(P, Q, row, col, att_s, att_d, lin_W, a_s, a_d, z);
  k_acc<<<E2C / 256, 256, 0, stream>>>(src2, dst2, a_s, a_d, z, denom, numer);
  k_gate<<<EE / 256, 256, 0, stream>>>(a_s, a_d, z, denom, numer, gat_b, lin_W, lin_b,
                                       noise, tmp, gate);
  k_hash_build<<<EE / 256, 256, 0, stream>>>(row, col, gate, hKeys, hCnt, hGsum);
  k_edge_w<<<EE / 256, 256, 0, stream>>>(row, col, hKeys, hCnt, hGsum, wE, degsum, colCnt);
  k_scan<<<1, 1024, 0, stream>>>(colCnt, NN, colOffs, colCur);
  k_scatter_col<<<EE / 256, 256, 0, stream>>>(col, colCur, colEid);

  // 3-layer edge-weighted GCN
  k_gather<<<NN / 4, 256, 0, stream>>>(x, wE, row, colOffs, colEid, degsum, T);
  k_gemm128<<<NN / 4, 256, 0, stream>>>(T, W1, Hbuf);
  k_gather<<<NN / 4, 256, 0, stream>>>(Hbuf, wE, row, colOffs, colEid, degsum, T);
  k_gemm128<<<NN / 4, 256, 0, stream>>>(T, W2, Hbuf);
  k_gather<<<NN / 4, 256, 0, stream>>>(Hbuf, wE, row, colOffs, colEid, degsum, T);
  k_gemm128<<<NN / 4, 256, 0, stream>>>(T, W3, Hbuf);

  k_pool<<<NN / 64, 256, 0, stream>>>(Hbuf, gvec);
  k_final<<<1, 128, 0, stream>>>(gvec, Wc, out);
}